// Round 2
// baseline (312.663 us; speedup 1.0000x reference)
//
#include <hip/hip_runtime.h>

typedef __bf16 bf16;
typedef __bf16 bf16x8 __attribute__((ext_vector_type(8)));
typedef float floatx4 __attribute__((ext_vector_type(4)));

#define SEQ 4096
#define DM 1024
#define NH 16
#define HD 64

__device__ __forceinline__ bf16x8 load8(const bf16* p) {
    return *(const bf16x8*)p;
}

// fp32 -> bf16 cast, 8 elements/thread
__global__ __launch_bounds__(256) void cast_f32_bf16_kernel(
    const float* __restrict__ src, bf16* __restrict__ dst, int n8)
{
    int i = blockIdx.x * blockDim.x + threadIdx.x;
    if (i >= n8) return;
    const float4* s = (const float4*)src;
    float4 a = s[2 * i], b = s[2 * i + 1];
    bf16x8 o;
    o[0] = (bf16)a.x; o[1] = (bf16)a.y; o[2] = (bf16)a.z; o[3] = (bf16)a.w;
    o[4] = (bf16)b.x; o[5] = (bf16)b.y; o[6] = (bf16)b.z; o[7] = (bf16)b.w;
    *(bf16x8*)(dst + 8 * i) = o;
}

// C[M][N] = X[M][K] @ W[N][K]^T + bias(fp32), bf16 in, fp32 accum, TOUT out.
// One wave per 32(M) x 64(N) tile.
template <typename TOUT>
__global__ __launch_bounds__(64) void gemm_bias_kernel(
    const bf16* __restrict__ X,
    const bf16* __restrict__ W,
    const float* __restrict__ bias,
    TOUT* __restrict__ C,
    int M, int N, int K)
{
    const int lane = threadIdx.x;
    const int l15  = lane & 15;
    const int quad = lane >> 4;
    const int m0 = blockIdx.x * 32;
    const int n0 = blockIdx.y * 64;

    const bf16* Xrow0 = X + (size_t)(m0 + l15) * K + quad * 8;
    const bf16* Xrow1 = Xrow0 + (size_t)16 * K;
    const bf16* Wrow  = W + (size_t)(n0 + l15) * K + quad * 8;

    floatx4 acc[2][4] = {};

    for (int k = 0; k < K; k += 32) {
        bf16x8 a0 = load8(Xrow0 + k);
        bf16x8 a1 = load8(Xrow1 + k);
#pragma unroll
        for (int t = 0; t < 4; ++t) {
            bf16x8 b = load8(Wrow + (size_t)(t * 16) * K + k);
            acc[0][t] = __builtin_amdgcn_mfma_f32_16x16x32_bf16(a0, b, acc[0][t], 0, 0, 0);
            acc[1][t] = __builtin_amdgcn_mfma_f32_16x16x32_bf16(a1, b, acc[1][t], 0, 0, 0);
        }
    }

#pragma unroll
    for (int t = 0; t < 4; ++t) {
        int n = n0 + t * 16 + l15;
        float bv = bias[n];
#pragma unroll
        for (int a = 0; a < 2; ++a) {
#pragma unroll
            for (int r = 0; r < 4; ++r) {
                int m = m0 + a * 16 + quad * 4 + r;
                C[(size_t)m * N + n] = (TOUT)(acc[a][t][r] + bv);
            }
        }
    }
}

// Sliding-window attention, one wave per (16-query tile, head).
// Q,K,V,ctx layout: [S][DM] with head h at cols [h*64, h*64+64).
__global__ __launch_bounds__(64) void swattn_kernel(
    const bf16* __restrict__ Q,
    const bf16* __restrict__ Km,
    const bf16* __restrict__ V,
    bf16* __restrict__ ctx)
{
    __shared__ bf16 Plds[16][40];
    __shared__ bf16 Vt[64][40];

    const int lane = threadIdx.x;
    const int l15  = lane & 15;
    const int quad = lane >> 4;
    const int q0   = blockIdx.x * 16;
    const int h    = blockIdx.y;
    const int hoff = h * HD;

    const bf16* qbase = Q + (size_t)(q0 + l15) * DM + hoff + quad * 8;
    bf16x8 aq0 = load8(qbase);
    bf16x8 aq1 = load8(qbase + 32);

    float mrow[4] = {-INFINITY, -INFINITY, -INFINITY, -INFINITY};
    float lrow[4] = {0.f, 0.f, 0.f, 0.f};
    floatx4 o[4] = {};

    for (int kb = q0 - 64; kb <= q0 + 64; kb += 32) {
        __syncthreads();  // WAR on Plds/Vt from previous iteration

        // stage V^T tile: Vt[d][k] = V[kb+k][hoff+d]
#pragma unroll
        for (int it = 0; it < 4; ++it) {
            int krow = it * 8 + (lane >> 3);
            int kg = kb + krow;
            kg = kg < 0 ? 0 : (kg > SEQ - 1 ? SEQ - 1 : kg);
            int d0 = (lane & 7) * 8;
            bf16x8 vv = load8(V + (size_t)kg * DM + hoff + d0);
#pragma unroll
            for (int j = 0; j < 8; ++j)
                Vt[d0 + j][krow] = vv[j];
        }

        // scores: S[q][key] for 32 keys
        floatx4 sa[2];
#pragma unroll
        for (int nt = 0; nt < 2; ++nt) {
            int key = kb + nt * 16 + l15;
            int kc = key < 0 ? 0 : (key > SEQ - 1 ? SEQ - 1 : key);
            const bf16* kr = Km + (size_t)kc * DM + hoff + quad * 8;
            bf16x8 b0 = load8(kr);
            bf16x8 b1 = load8(kr + 32);
            floatx4 acc = {};
            acc = __builtin_amdgcn_mfma_f32_16x16x32_bf16(aq0, b0, acc, 0, 0, 0);
            acc = __builtin_amdgcn_mfma_f32_16x16x32_bf16(aq1, b1, acc, 0, 0, 0);
            sa[nt] = acc;
        }

        // online softmax (per q-row; rows live in a 16-lane quad group)
#pragma unroll
        for (int r = 0; r < 4; ++r) {
            int q = q0 + quad * 4 + r;
            int k0i = kb + l15;
            int k1i = kb + 16 + l15;
            float v0 = sa[0][r] * 0.125f;
            float v1 = sa[1][r] * 0.125f;
            int d0 = q - k0i, d1 = q - k1i;
            if (d0 > 64 || d0 < -64 || k0i < 0 || k0i >= SEQ) v0 = -1e9f;
            if (d1 > 64 || d1 < -64 || k1i < 0 || k1i >= SEQ) v1 = -1e9f;

            float mx = fmaxf(v0, v1);
            mx = fmaxf(mx, __shfl_xor(mx, 1));
            mx = fmaxf(mx, __shfl_xor(mx, 2));
            mx = fmaxf(mx, __shfl_xor(mx, 4));
            mx = fmaxf(mx, __shfl_xor(mx, 8));
            float mnew = fmaxf(mrow[r], mx);
            float alpha = __expf(mrow[r] - mnew);
            float p0 = __expf(v0 - mnew);
            float p1 = __expf(v1 - mnew);
            float rs = p0 + p1;
            rs += __shfl_xor(rs, 1);
            rs += __shfl_xor(rs, 2);
            rs += __shfl_xor(rs, 4);
            rs += __shfl_xor(rs, 8);
            lrow[r] = lrow[r] * alpha + rs;
            mrow[r] = mnew;
#pragma unroll
            for (int t = 0; t < 4; ++t) o[t][r] *= alpha;
            Plds[quad * 4 + r][l15]      = (bf16)p0;
            Plds[quad * 4 + r][16 + l15] = (bf16)p1;
        }

        __syncthreads();  // Plds/Vt writes -> frag reads

        bf16x8 ap = load8(&Plds[l15][quad * 8]);
#pragma unroll
        for (int t = 0; t < 4; ++t) {
            bf16x8 bv = load8(&Vt[t * 16 + l15][quad * 8]);
            o[t] = __builtin_amdgcn_mfma_f32_16x16x32_bf16(ap, bv, o[t], 0, 0, 0);
        }
    }

#pragma unroll
    for (int t = 0; t < 4; ++t) {
#pragma unroll
        for (int r = 0; r < 4; ++r) {
            int q = q0 + quad * 4 + r;
            ctx[(size_t)q * DM + hoff + t * 16 + l15] = (bf16)(o[t][r] / lrow[r]);
        }
    }
}

extern "C" void kernel_launch(void* const* d_in, const int* in_sizes, int n_in,
                              void* d_out, int out_size, void* d_ws, size_t ws_size,
                              hipStream_t stream) {
    const float* x  = (const float*)d_in[0];
    const float* Wq = (const float*)d_in[1];
    const float* bq = (const float*)d_in[2];
    const float* Wk = (const float*)d_in[3];
    const float* bk = (const float*)d_in[4];
    const float* Wv = (const float*)d_in[5];
    const float* bv = (const float*)d_in[6];
    const float* Wo = (const float*)d_in[7];
    const float* bo = (const float*)d_in[8];
    float* out = (float*)d_out;

    const size_t XN = (size_t)SEQ * DM;   // 4.2M
    const size_t WN = (size_t)DM * DM;    // 1M

    bf16* xb  = (bf16*)d_ws;
    bf16* Wqb = xb + XN;
    bf16* Wkb = Wqb + WN;
    bf16* Wvb = Wkb + WN;
    bf16* Wob = Wvb + WN;
    bf16* Qb  = Wob + WN;
    bf16* Kb  = Qb + XN;
    bf16* Vb  = Kb + XN;
    bf16* ctx = Vb + XN;

    // casts
    {
        int n8 = (int)(XN / 8);
        cast_f32_bf16_kernel<<<(n8 + 255) / 256, 256, 0, stream>>>(x, xb, n8);
        int w8 = (int)(WN / 8);
        cast_f32_bf16_kernel<<<(w8 + 255) / 256, 256, 0, stream>>>(Wq, Wqb, w8);
        cast_f32_bf16_kernel<<<(w8 + 255) / 256, 256, 0, stream>>>(Wk, Wkb, w8);
        cast_f32_bf16_kernel<<<(w8 + 255) / 256, 256, 0, stream>>>(Wv, Wvb, w8);
        cast_f32_bf16_kernel<<<(w8 + 255) / 256, 256, 0, stream>>>(Wo, Wob, w8);
    }

    dim3 gg(SEQ / 32, DM / 64), bb(64);
    gemm_bias_kernel<bf16><<<gg, bb, 0, stream>>>(xb, Wqb, bq, Qb, SEQ, DM, DM);
    gemm_bias_kernel<bf16><<<gg, bb, 0, stream>>>(xb, Wkb, bk, Kb, SEQ, DM, DM);
    gemm_bias_kernel<bf16><<<gg, bb, 0, stream>>>(xb, Wvb, bv, Vb, SEQ, DM, DM);
    swattn_kernel<<<dim3(SEQ / 16, NH), bb, 0, stream>>>(Qb, Kb, Vb, ctx);
    gemm_bias_kernel<float><<<gg, bb, 0, stream>>>(ctx, Wob, bo, out, SEQ, DM, DM);
}

// Round 3
// 188.908 us; speedup vs baseline: 1.6551x; 1.6551x over previous
//
#include <hip/hip_runtime.h>

typedef __bf16 bf16;
typedef __bf16 bf16x8 __attribute__((ext_vector_type(8)));
typedef float floatx4 __attribute__((ext_vector_type(4)));

#define SEQ 4096
#define DM 1024
#define NH 16
#define HD 64
#define SD 3072   // QKV concat stride

__device__ __forceinline__ bf16x8 load8(const bf16* p) {
    return *(const bf16x8*)p;
}

// async 16B/lane global -> LDS (wave-uniform LDS base + lane*16)
__device__ __forceinline__ void async_ld16(const bf16* g, bf16* l) {
    __builtin_amdgcn_global_load_lds(
        (const __attribute__((address_space(1))) unsigned int*)g,
        (__attribute__((address_space(3))) unsigned int*)l,
        16, 0, 0);
}

// fp32 -> bf16 cast, 8 elements/thread
__global__ __launch_bounds__(256) void cast_f32_bf16_kernel(
    const float* __restrict__ src, bf16* __restrict__ dst, int n8)
{
    int i = blockIdx.x * blockDim.x + threadIdx.x;
    if (i >= n8) return;
    const float4* s = (const float4*)src;
    float4 a = s[2 * i], b = s[2 * i + 1];
    bf16x8 o;
    o[0] = (bf16)a.x; o[1] = (bf16)a.y; o[2] = (bf16)a.z; o[3] = (bf16)a.w;
    o[4] = (bf16)b.x; o[5] = (bf16)b.y; o[6] = (bf16)b.z; o[7] = (bf16)b.w;
    *(bf16x8*)(dst + 8 * i) = o;
}

__global__ __launch_bounds__(256) void bias_concat_kernel(
    const float* __restrict__ b0, const float* __restrict__ b1,
    const float* __restrict__ b2, float* __restrict__ dst)
{
    int i = blockIdx.x * blockDim.x + threadIdx.x;
    if (i >= 3 * DM) return;
    dst[i] = i < DM ? b0[i] : (i < 2 * DM ? b1[i - DM] : b2[i - 2 * DM]);
}

// C[M][N] = A[M][K] @ B[N][K]^T + bias, bf16 in, fp32 accum, TOUT out.
// m97 structure: 256 threads, BM x 128 tile, BK=32, global_load_lds staging.
template <int BM, typename TOUT>
__global__ __launch_bounds__(256) void gemm_lds_kernel(
    const bf16* __restrict__ A,
    const bf16* __restrict__ B,
    const float* __restrict__ bias,
    TOUT* __restrict__ C,
    int M, int N, int K)
{
    constexpr int MI = BM / 32;            // 16-row blocks per wave (m-dir)
    __shared__ bf16 As[BM * 32];
    __shared__ bf16 Bs[128 * 32];

    const int tid  = threadIdx.x;
    const int wave = tid >> 6;
    const int lane = tid & 63;
    const int l15  = lane & 15;
    const int quad = lane >> 4;
    const int m0 = blockIdx.x * BM;
    const int n0 = blockIdx.y * 128;

    const int wm = (wave & 1) * (BM / 2);
    const int wn = (wave >> 1) * 64;

    // staging assignments: chunks of 16 rows x 32 cols (1024 B)
    const int lrow = lane >> 2;            // 0..15
    const int lcol = (lane & 3) * 8;       // element offset in row

    const bf16* aptr[2]; bf16* alds[2]; int na = 0;
#pragma unroll
    for (int c = wave; c < BM / 16; c += 4) {
        aptr[na] = A + (size_t)(m0 + c * 16 + lrow) * K + lcol;
        alds[na] = As + c * 512;
        ++na;
    }
    const bf16* bptr[2]; bf16* blds[2];
    {
        int i = 0;
#pragma unroll
        for (int c = wave; c < 8; c += 4) {
            bptr[i] = B + (size_t)(n0 + c * 16 + lrow) * K + lcol;
            blds[i] = Bs + c * 512;
            ++i;
        }
    }

    floatx4 acc[MI][4] = {};

    for (int k0 = 0; k0 < K; k0 += 32) {
        __syncthreads();   // WAR: prior frag reads done before overwrite
#pragma unroll
        for (int i = 0; i < 2; ++i)
            if (i < na) async_ld16(aptr[i] + k0, alds[i]);
#pragma unroll
        for (int i = 0; i < 2; ++i)
            async_ld16(bptr[i] + k0, blds[i]);
        __syncthreads();   // barrier drain (vmcnt(0)) makes staged data visible

        bf16x8 af[MI], bfr[4];
#pragma unroll
        for (int i = 0; i < MI; ++i)
            af[i] = load8(As + (wm + i * 16 + l15) * 32 + quad * 8);
#pragma unroll
        for (int j = 0; j < 4; ++j)
            bfr[j] = load8(Bs + (wn + j * 16 + l15) * 32 + quad * 8);
#pragma unroll
        for (int i = 0; i < MI; ++i)
#pragma unroll
            for (int j = 0; j < 4; ++j)
                acc[i][j] = __builtin_amdgcn_mfma_f32_16x16x32_bf16(af[i], bfr[j], acc[i][j], 0, 0, 0);
    }

#pragma unroll
    for (int j = 0; j < 4; ++j) {
        int n = n0 + wn + j * 16 + l15;
        float bv = bias[n];
#pragma unroll
        for (int i = 0; i < MI; ++i) {
#pragma unroll
            for (int r = 0; r < 4; ++r) {
                int m = m0 + wm + i * 16 + quad * 4 + r;
                C[(size_t)m * N + n] = (TOUT)(acc[i][j][r] + bv);
            }
        }
    }
}

// Sliding-window attention, one wave per (16-query tile, head).
// QKV layout: [S][3072]: Q at col h*64, K at 1024+h*64, V at 2048+h*64.
__global__ __launch_bounds__(64) void swattn_kernel(
    const bf16* __restrict__ QKV,
    bf16* __restrict__ ctx)
{
    __shared__ bf16 Plds[16][40];
    __shared__ bf16 Vt[64][40];

    const int lane = threadIdx.x;
    const int l15  = lane & 15;
    const int quad = lane >> 4;
    const int q0   = blockIdx.x * 16;
    const int h    = blockIdx.y;
    const int hoff = h * HD;

    const bf16* qbase = QKV + (size_t)(q0 + l15) * SD + hoff + quad * 8;
    bf16x8 aq0 = load8(qbase);
    bf16x8 aq1 = load8(qbase + 32);

    float mrow[4] = {-INFINITY, -INFINITY, -INFINITY, -INFINITY};
    float lrow[4] = {0.f, 0.f, 0.f, 0.f};
    floatx4 o[4] = {};

    for (int kb = q0 - 64; kb <= q0 + 64; kb += 32) {
        __syncthreads();  // WAR on Plds/Vt from previous iteration

        // stage V^T tile: Vt[d][k] = V[kb+k][hoff+d]
#pragma unroll
        for (int it = 0; it < 4; ++it) {
            int krow = it * 8 + (lane >> 3);
            int kg = kb + krow;
            kg = kg < 0 ? 0 : (kg > SEQ - 1 ? SEQ - 1 : kg);
            int d0 = (lane & 7) * 8;
            bf16x8 vv = load8(QKV + (size_t)kg * SD + 2048 + hoff + d0);
#pragma unroll
            for (int j = 0; j < 8; ++j)
                Vt[d0 + j][krow] = vv[j];
        }

        // scores: S[q][key] for 32 keys
        floatx4 sa[2];
#pragma unroll
        for (int nt = 0; nt < 2; ++nt) {
            int key = kb + nt * 16 + l15;
            int kc = key < 0 ? 0 : (key > SEQ - 1 ? SEQ - 1 : key);
            const bf16* kr = QKV + (size_t)kc * SD + 1024 + hoff + quad * 8;
            bf16x8 b0 = load8(kr);
            bf16x8 b1 = load8(kr + 32);
            floatx4 acc = {};
            acc = __builtin_amdgcn_mfma_f32_16x16x32_bf16(aq0, b0, acc, 0, 0, 0);
            acc = __builtin_amdgcn_mfma_f32_16x16x32_bf16(aq1, b1, acc, 0, 0, 0);
            sa[nt] = acc;
        }

        // online softmax (per q-row; rows live in a 16-lane quad group)
#pragma unroll
        for (int r = 0; r < 4; ++r) {
            int q = q0 + quad * 4 + r;
            int k0i = kb + l15;
            int k1i = kb + 16 + l15;
            float v0 = sa[0][r] * 0.125f;
            float v1 = sa[1][r] * 0.125f;
            int d0 = q - k0i, d1 = q - k1i;
            if (d0 > 64 || d0 < -64 || k0i < 0 || k0i >= SEQ) v0 = -1e9f;
            if (d1 > 64 || d1 < -64 || k1i < 0 || k1i >= SEQ) v1 = -1e9f;

            float mx = fmaxf(v0, v1);
            mx = fmaxf(mx, __shfl_xor(mx, 1));
            mx = fmaxf(mx, __shfl_xor(mx, 2));
            mx = fmaxf(mx, __shfl_xor(mx, 4));
            mx = fmaxf(mx, __shfl_xor(mx, 8));
            float mnew = fmaxf(mrow[r], mx);
            float alpha = __expf(mrow[r] - mnew);
            float p0 = __expf(v0 - mnew);
            float p1 = __expf(v1 - mnew);
            float rs = p0 + p1;
            rs += __shfl_xor(rs, 1);
            rs += __shfl_xor(rs, 2);
            rs += __shfl_xor(rs, 4);
            rs += __shfl_xor(rs, 8);
            lrow[r] = lrow[r] * alpha + rs;
            mrow[r] = mnew;
#pragma unroll
            for (int t = 0; t < 4; ++t) o[t][r] *= alpha;
            Plds[quad * 4 + r][l15]      = (bf16)p0;
            Plds[quad * 4 + r][16 + l15] = (bf16)p1;
        }

        __syncthreads();  // Plds/Vt writes -> frag reads

        bf16x8 ap = load8(&Plds[l15][quad * 8]);
#pragma unroll
        for (int t = 0; t < 4; ++t) {
            bf16x8 bv = load8(&Vt[t * 16 + l15][quad * 8]);
            o[t] = __builtin_amdgcn_mfma_f32_16x16x32_bf16(ap, bv, o[t], 0, 0, 0);
        }
    }

#pragma unroll
    for (int t = 0; t < 4; ++t) {
#pragma unroll
        for (int r = 0; r < 4; ++r) {
            int q = q0 + quad * 4 + r;
            ctx[(size_t)q * DM + hoff + t * 16 + l15] = (bf16)(o[t][r] / lrow[r]);
        }
    }
}

extern "C" void kernel_launch(void* const* d_in, const int* in_sizes, int n_in,
                              void* d_out, int out_size, void* d_ws, size_t ws_size,
                              hipStream_t stream) {
    const float* x  = (const float*)d_in[0];
    const float* Wq = (const float*)d_in[1];
    const float* bq = (const float*)d_in[2];
    const float* Wk = (const float*)d_in[3];
    const float* bk = (const float*)d_in[4];
    const float* Wv = (const float*)d_in[5];
    const float* bv = (const float*)d_in[6];
    const float* Wo = (const float*)d_in[7];
    const float* bo = (const float*)d_in[8];
    float* out = (float*)d_out;

    const size_t XN = (size_t)SEQ * DM;   // 4.2M
    const size_t WN = (size_t)DM * DM;    // 1M

    bf16* xb   = (bf16*)d_ws;
    bf16* Wcat = xb + XN;                 // [3072][1024]
    bf16* Wob  = Wcat + 3 * WN;
    bf16* QKV  = Wob + WN;                // [4096][3072]
    bf16* ctx  = QKV + 3 * XN;            // [4096][1024]
    float* bcat = (float*)(ctx + XN);     // [3072]

    // casts
    int n8 = (int)(XN / 8);
    int w8 = (int)(WN / 8);
    cast_f32_bf16_kernel<<<(n8 + 255) / 256, 256, 0, stream>>>(x, xb, n8);
    cast_f32_bf16_kernel<<<(w8 + 255) / 256, 256, 0, stream>>>(Wq, Wcat, w8);
    cast_f32_bf16_kernel<<<(w8 + 255) / 256, 256, 0, stream>>>(Wk, Wcat + WN, w8);
    cast_f32_bf16_kernel<<<(w8 + 255) / 256, 256, 0, stream>>>(Wv, Wcat + 2 * WN, w8);
    cast_f32_bf16_kernel<<<(w8 + 255) / 256, 256, 0, stream>>>(Wo, Wob, w8);
    bias_concat_kernel<<<(3 * DM + 255) / 256, 256, 0, stream>>>(bq, bk, bv, bcat);

    // fused QKV projection: [4096,1024] @ [3072,1024]^T -> [4096,3072]
    gemm_lds_kernel<128, bf16><<<dim3(SEQ / 128, SD / 128), 256, 0, stream>>>(
        xb, Wcat, bcat, QKV, SEQ, SD, DM);

    swattn_kernel<<<dim3(SEQ / 16, NH), 64, 0, stream>>>(QKV, ctx);

    // out projection: [4096,1024] @ [1024,1024]^T -> fp32 out
    gemm_lds_kernel<64, float><<<dim3(SEQ / 64, DM / 128), 256, 0, stream>>>(
        ctx, Wob, bo, out, SEQ, DM, DM);
}

// Round 5
// 186.011 us; speedup vs baseline: 1.6809x; 1.0156x over previous
//
#include <hip/hip_runtime.h>

typedef __bf16 bf16;
typedef __bf16 bf16x8 __attribute__((ext_vector_type(8)));
typedef __bf16 bf16x4 __attribute__((ext_vector_type(4)));
typedef float floatx4 __attribute__((ext_vector_type(4)));

#define SEQ 4096
#define DM 1024
#define NH 16
#define HD 64
#define SD 3072   // QKV concat stride

__device__ __forceinline__ floatx4 mfma32(bf16x8 a, bf16x8 b, floatx4 c) {
    return __builtin_amdgcn_mfma_f32_16x16x32_bf16(a, b, c, 0, 0, 0);
}

__device__ __forceinline__ bf16x8 load8(const bf16* p) {
    return *(const bf16x8*)p;
}

// async 16B/lane global -> LDS (wave-uniform LDS base + lane*16)
__device__ __forceinline__ void async_ld16(const bf16* g, bf16* l) {
    __builtin_amdgcn_global_load_lds(
        (const __attribute__((address_space(1))) unsigned int*)g,
        (__attribute__((address_space(3))) unsigned int*)l,
        16, 0, 0);
}

// fused prep: cast x, Wq,Wk,Wv,Wo to bf16; concat biases to fp32 bcat.
// blocks 0..4095: casts (1M chunks of 8). block 4096: bias concat.
__global__ __launch_bounds__(256) void prep_kernel(
    const float* __restrict__ x,  const float* __restrict__ Wq,
    const float* __restrict__ Wk, const float* __restrict__ Wv,
    const float* __restrict__ Wo, const float* __restrict__ bq,
    const float* __restrict__ bk, const float* __restrict__ bv,
    bf16* __restrict__ xb, bf16* __restrict__ Wcat,
    bf16* __restrict__ Wob, float* __restrict__ bcat)
{
    const int WN8 = 131072;           // (1024*1024)/8
    const int XN8 = 524288;           // (4096*1024)/8
    int b = blockIdx.x;
    if (b == 4096) {
        for (int k = threadIdx.x; k < 3 * DM; k += 256)
            bcat[k] = k < DM ? bq[k] : (k < 2 * DM ? bk[k - DM] : bv[k - 2 * DM]);
        return;
    }
    int c = b * 256 + threadIdx.x;
    const float* src; bf16* dst;
    if (c < XN8)              { src = x;  dst = xb; }
    else if (c < XN8 + WN8)   { src = Wq; dst = Wcat;                 c -= XN8; }
    else if (c < XN8 + 2*WN8) { src = Wk; dst = Wcat + (size_t)DM*DM;     c -= XN8 + WN8; }
    else if (c < XN8 + 3*WN8) { src = Wv; dst = Wcat + (size_t)2*DM*DM;   c -= XN8 + 2*WN8; }
    else                      { src = Wo; dst = Wob;                  c -= XN8 + 3*WN8; }
    float4 a = ((const float4*)src)[2 * c], d2 = ((const float4*)src)[2 * c + 1];
    bf16x8 o;
    o[0] = (bf16)a.x;  o[1] = (bf16)a.y;  o[2] = (bf16)a.z;  o[3] = (bf16)a.w;
    o[4] = (bf16)d2.x; o[5] = (bf16)d2.y; o[6] = (bf16)d2.z; o[7] = (bf16)d2.w;
    *(bf16x8*)(dst + 8 * (size_t)c) = o;
}

// C[M][N] = A[M][K] @ B[N][K]^T + bias, bf16 in, fp32 accum, TOUT out.
// m97 structure + operand-swapped mfma so each lane holds 4 consecutive
// output columns -> packed stores.
template <int BM, typename TOUT>
__global__ __launch_bounds__(256) void gemm_lds_kernel(
    const bf16* __restrict__ A,
    const bf16* __restrict__ B,
    const float* __restrict__ bias,
    TOUT* __restrict__ C,
    int M, int N, int K)
{
    constexpr int MI = BM / 32;
    __shared__ bf16 As[BM * 32];
    __shared__ bf16 Bs[128 * 32];

    const int tid  = threadIdx.x;
    const int wave = tid >> 6;
    const int lane = tid & 63;
    const int l15  = lane & 15;
    const int quad = lane >> 4;
    const int m0 = blockIdx.x * BM;
    const int n0 = blockIdx.y * 128;

    const int wm = (wave & 1) * (BM / 2);
    const int wn = (wave >> 1) * 64;

    const int lrow = lane >> 2;
    const int lcol = (lane & 3) * 8;

    const bf16* aptr[2]; bf16* alds[2]; int na = 0;
#pragma unroll
    for (int c = wave; c < BM / 16; c += 4) {
        aptr[na] = A + (size_t)(m0 + c * 16 + lrow) * K + lcol;
        alds[na] = As + c * 512;
        ++na;
    }
    const bf16* bptr[2]; bf16* blds[2];
    {
        int i = 0;
#pragma unroll
        for (int c = wave; c < 8; c += 4) {
            bptr[i] = B + (size_t)(n0 + c * 16 + lrow) * K + lcol;
            blds[i] = Bs + c * 512;
            ++i;
        }
    }

    floatx4 acc[MI][4] = {};

    for (int k0 = 0; k0 < K; k0 += 32) {
        __syncthreads();
#pragma unroll
        for (int i = 0; i < 2; ++i)
            if (i < na) async_ld16(aptr[i] + k0, alds[i]);
#pragma unroll
        for (int i = 0; i < 2; ++i)
            async_ld16(bptr[i] + k0, blds[i]);
        __syncthreads();

        bf16x8 af[MI], bfr[4];
#pragma unroll
        for (int i = 0; i < MI; ++i)
            af[i] = load8(As + (wm + i * 16 + l15) * 32 + quad * 8);
#pragma unroll
        for (int j = 0; j < 4; ++j)
            bfr[j] = load8(Bs + (wn + j * 16 + l15) * 32 + quad * 8);
        // swapped: a-operand = W rows (m-dim = output col), b-operand = X rows
        // (n-dim = output row). D: col(l15)=x-row, row(quad*4+r)=out col.
#pragma unroll
        for (int i = 0; i < MI; ++i)
#pragma unroll
            for (int j = 0; j < 4; ++j)
                acc[i][j] = mfma32(bfr[j], af[i], acc[i][j]);
    }

#pragma unroll
    for (int i = 0; i < MI; ++i) {
        int xm = m0 + wm + i * 16 + l15;
#pragma unroll
        for (int j = 0; j < 4; ++j) {
            int cn = n0 + wn + j * 16 + quad * 4;
            float4 bv = *(const float4*)(bias + cn);
            float v0 = acc[i][j][0] + bv.x;
            float v1 = acc[i][j][1] + bv.y;
            float v2 = acc[i][j][2] + bv.z;
            float v3 = acc[i][j][3] + bv.w;
            if constexpr (sizeof(TOUT) == 2) {
                bf16x4 o = {(bf16)v0, (bf16)v1, (bf16)v2, (bf16)v3};
                *(bf16x4*)((bf16*)C + (size_t)xm * N + cn) = o;
            } else {
                float4 o = {v0, v1, v2, v3};
                *(float4*)((float*)C + (size_t)xm * N + cn) = o;
            }
        }
    }
}

// Sliding-window attention: 64 queries x 1 head per block, 4 waves.
// Wave w: queries q0+16w..+15, key window [q0+16w-64, q0+16w+80) = 144 keys
// = block V-tile cols [16w, 16w+144). One-shot softmax over 9 score tiles.
__global__ __launch_bounds__(256, 4) void swattn_kernel(
    const bf16* __restrict__ QKV,
    bf16* __restrict__ ctx)
{
    __shared__ bf16 Vt[64][216];     // V^T, block keys [q0-64, q0+152)
    __shared__ bf16 Pc[4][16][40];   // per-wave P chunk (32 keys)
    __shared__ float lred[4][16];

    const int tid  = threadIdx.x;
    const int wave = tid >> 6;
    const int lane = tid & 63;
    const int l15  = lane & 15;
    const int quad = lane >> 4;
    const int q0   = blockIdx.x * 64;
    const int h    = blockIdx.y;
    const int hoff = h * HD;
    const int kbase = q0 - 64;

    // stage V^T: Vt[d][c] = V[clamp(kbase+c)][hoff+d], c in [0,216)
    for (int task = tid; task < 432; task += 256) {
        int kg = task % 54, dc = task / 54;
        bf16x8 r[4];
#pragma unroll
        for (int i = 0; i < 4; ++i) {
            int gk = kbase + 4 * kg + i;
            gk = gk < 0 ? 0 : (gk > SEQ - 1 ? SEQ - 1 : gk);
            r[i] = load8(QKV + (size_t)gk * SD + 2048 + hoff + dc * 8);
        }
#pragma unroll
        for (int j = 0; j < 8; ++j) {
            bf16x4 w = { r[0][j], r[1][j], r[2][j], r[3][j] };
            *(bf16x4*)&Vt[dc * 8 + j][4 * kg] = w;
        }
    }

    // Q a-frags
    const int qrow = q0 + wave * 16 + l15;
    const bf16* qb = QKV + (size_t)qrow * SD + hoff + quad * 8;
    bf16x8 aq0 = load8(qb), aq1 = load8(qb + 32);

    // scores for 9 key tiles (K b-frags straight from global)
    const int ws = kbase + wave * 16;   // wave window start (global key)
    floatx4 s[9];
#pragma unroll
    for (int st = 0; st < 9; ++st) {
        int kr = ws + st * 16 + l15;
        int kc2 = kr < 0 ? 0 : (kr > SEQ - 1 ? SEQ - 1 : kr);
        const bf16* kp = QKV + (size_t)kc2 * SD + 1024 + hoff + quad * 8;
        bf16x8 b0 = load8(kp), b1 = load8(kp + 32);
        floatx4 acc = {};
        acc = mfma32(aq0, b0, acc);
        acc = mfma32(aq1, b1, acc);
        s[st] = acc;
    }

    // mask + one-shot softmax; row = quad*4+r, col(key) = 16*st + l15
#pragma unroll
    for (int r = 0; r < 4; ++r) {
        int row = quad * 4 + r;
        float mx = -INFINITY;
#pragma unroll
        for (int st = 0; st < 9; ++st) {
            int j = st * 16 + l15;
            int gk = ws + j;
            bool ok = (j >= row) && (j <= 128 + row) && (gk >= 0) && (gk < SEQ);
            float v = ok ? s[st][r] * 0.125f : -1e30f;
            s[st][r] = v;
            mx = fmaxf(mx, v);
        }
        mx = fmaxf(mx, __shfl_xor(mx, 1));
        mx = fmaxf(mx, __shfl_xor(mx, 2));
        mx = fmaxf(mx, __shfl_xor(mx, 4));
        mx = fmaxf(mx, __shfl_xor(mx, 8));
        float sum = 0.f;
#pragma unroll
        for (int st = 0; st < 9; ++st) {
            float p = __expf(s[st][r] - mx);
            s[st][r] = p;
            sum += p;
        }
        sum += __shfl_xor(sum, 1);
        sum += __shfl_xor(sum, 2);
        sum += __shfl_xor(sum, 4);
        sum += __shfl_xor(sum, 8);
        lred[wave][row] = sum;
    }

    __syncthreads();   // Vt staging visible to all waves

    // PV, operand-swapped: a = V^T frag (m-dim = d), b = P frag (n-dim = q).
    // O^T accumulator: row(quad*4+r) = d, col(l15) = query.
    floatx4 ot[4] = {};
#pragma unroll
    for (int kc = 0; kc < 5; ++kc) {
#pragma unroll
        for (int r = 0; r < 4; ++r) {
            int row = quad * 4 + r;
            Pc[wave][row][l15] = (bf16)s[2 * kc][r];
            if (kc < 4)
                Pc[wave][row][16 + l15] = (bf16)s[2 * kc + 1][r];
            else
                Pc[wave][row][16 + l15] = (bf16)0.f;
        }
        // wave-local LDS: DS ops execute in program order within a wave
        bf16x8 pb = load8(&Pc[wave][l15][quad * 8]);
#pragma unroll
        for (int dt = 0; dt < 4; ++dt) {
            bf16x8 va = load8(&Vt[dt * 16 + l15][wave * 16 + kc * 32 + quad * 8]);
            ot[dt] = mfma32(va, pb, ot[dt]);
        }
    }

    float linv = 1.0f / lred[wave][l15];
#pragma unroll
    for (int dt = 0; dt < 4; ++dt) {
        bf16x4 o4;
#pragma unroll
        for (int r = 0; r < 4; ++r) o4[r] = (bf16)(ot[dt][r] * linv);
        // lane writes ctx[q = q0+16w+l15][hoff + dt*16 + quad*4 .. +3]
        *(bf16x4*)(ctx + (size_t)qrow * DM + hoff + dt * 16 + quad * 4) = o4;
    }
}

extern "C" void kernel_launch(void* const* d_in, const int* in_sizes, int n_in,
                              void* d_out, int out_size, void* d_ws, size_t ws_size,
                              hipStream_t stream) {
    const float* x  = (const float*)d_in[0];
    const float* Wq = (const float*)d_in[1];
    const float* bq = (const float*)d_in[2];
    const float* Wk = (const float*)d_in[3];
    const float* bk = (const float*)d_in[4];
    const float* Wv = (const float*)d_in[5];
    const float* bv = (const float*)d_in[6];
    const float* Wo = (const float*)d_in[7];
    const float* bo = (const float*)d_in[8];
    float* out = (float*)d_out;

    const size_t XN = (size_t)SEQ * DM;
    const size_t WN = (size_t)DM * DM;

    bf16* xb   = (bf16*)d_ws;
    bf16* Wcat = xb + XN;                 // [3072][1024]
    bf16* Wob  = Wcat + 3 * WN;
    bf16* QKV  = Wob + WN;                // [4096][3072]
    bf16* ctx  = QKV + 3 * XN;            // [4096][1024]
    float* bcat = (float*)(ctx + XN);     // [3072]

    prep_kernel<<<4097, 256, 0, stream>>>(x, Wq, Wk, Wv, Wo, bq, bk, bv,
                                          xb, Wcat, Wob, bcat);

    gemm_lds_kernel<128, bf16><<<dim3(SEQ / 128, SD / 128), 256, 0, stream>>>(
        xb, Wcat, bcat, QKV, SEQ, SD, DM);

    swattn_kernel<<<dim3(SEQ / 64, NH), 256, 0, stream>>>(QKV, ctx);

    gemm_lds_kernel<64, float><<<dim3(SEQ / 64, DM / 128), 256, 0, stream>>>(
        ctx, Wob, bo, out, SEQ, DM, DM);
}

// Round 6
// 170.992 us; speedup vs baseline: 1.8285x; 1.0878x over previous
//
#include <hip/hip_runtime.h>
#include <type_traits>

typedef __bf16 bf16;
typedef __bf16 bf16x8 __attribute__((ext_vector_type(8)));
typedef __bf16 bf16x4 __attribute__((ext_vector_type(4)));
typedef float floatx4 __attribute__((ext_vector_type(4)));

#define SEQ 4096
#define DM 1024
#define NH 16
#define HD 64
#define GUARD 64

__device__ __forceinline__ floatx4 mfma32(bf16x8 a, bf16x8 b, floatx4 c) {
    return __builtin_amdgcn_mfma_f32_16x16x32_bf16(a, b, c, 0, 0, 0);
}

__device__ __forceinline__ bf16x8 load8(const bf16* p) {
    return *(const bf16x8*)p;
}

__device__ __forceinline__ void async_ld16(const bf16* g, bf16* l) {
    __builtin_amdgcn_global_load_lds(
        (const __attribute__((address_space(1))) unsigned int*)g,
        (__attribute__((address_space(3))) unsigned int*)l,
        16, 0, 0);
}

// fused prep: cast x, Wq,Wk,Wv,Wo to bf16; concat biases to fp32 bcat.
__global__ __launch_bounds__(256) void prep_kernel(
    const float* __restrict__ x,  const float* __restrict__ Wq,
    const float* __restrict__ Wk, const float* __restrict__ Wv,
    const float* __restrict__ Wo, const float* __restrict__ bq,
    const float* __restrict__ bk, const float* __restrict__ bv,
    bf16* __restrict__ xb, bf16* __restrict__ Wcat,
    bf16* __restrict__ Wob, float* __restrict__ bcat)
{
    const int WN8 = 131072;           // (1024*1024)/8
    const int XN8 = 524288;           // (4096*1024)/8
    int b = blockIdx.x;
    if (b == 4096) {
        for (int k = threadIdx.x; k < 3 * DM; k += 256)
            bcat[k] = k < DM ? bq[k] : (k < 2 * DM ? bk[k - DM] : bv[k - 2 * DM]);
        return;
    }
    int c = b * 256 + threadIdx.x;
    const float* src; bf16* dst;
    if (c < XN8)              { src = x;  dst = xb; }
    else if (c < XN8 + WN8)   { src = Wq; dst = Wcat;                 c -= XN8; }
    else if (c < XN8 + 2*WN8) { src = Wk; dst = Wcat + (size_t)DM*DM;     c -= XN8 + WN8; }
    else if (c < XN8 + 3*WN8) { src = Wv; dst = Wcat + (size_t)2*DM*DM;   c -= XN8 + 2*WN8; }
    else                      { src = Wo; dst = Wob;                  c -= XN8 + 3*WN8; }
    float4 a = ((const float4*)src)[2 * c], d2 = ((const float4*)src)[2 * c + 1];
    bf16x8 o;
    o[0] = (bf16)a.x;  o[1] = (bf16)a.y;  o[2] = (bf16)a.z;  o[3] = (bf16)a.w;
    o[4] = (bf16)d2.x; o[5] = (bf16)d2.y; o[6] = (bf16)d2.z; o[7] = (bf16)d2.w;
    *(bf16x8*)(dst + 8 * (size_t)c) = o;
}

// ---- QKV projection GEMM: [4096,1024] @ [3072,1024]^T, head-major outputs.
// BM=128, BN=128, BK=64, XOR-swizzled LDS (2-way max bank aliasing).
// Q,K out: [h][s][64]. V out: transposed [h*64+d][SEQ] (guarded base).
__global__ __launch_bounds__(256) void gemm_qkv_kernel(
    const bf16* __restrict__ A,      // xb [4096][1024]
    const bf16* __restrict__ B,      // Wcat [3072][1024]
    const float* __restrict__ bias,  // bcat [3072]
    bf16* __restrict__ Qh, bf16* __restrict__ Kh, bf16* __restrict__ Vt)
{
    constexpr int K = DM;
    __shared__ bf16 As[128 * 64];
    __shared__ bf16 Bs[128 * 64];

    const int tid  = threadIdx.x;
    const int wave = tid >> 6;
    const int lane = tid & 63;
    const int l15  = lane & 15;
    const int quad = lane >> 4;
    const int m0 = blockIdx.x * 128;
    const int n0 = blockIdx.y * 128;
    const int wm = (wave & 1) * 64;
    const int wn = (wave >> 1) * 64;

    // staging: chunk = 8 rows x 64 cols (1024B). lane -> (row lane>>3,
    // LDS slot lane&7); global col chunk gc = (slot - row)&7  [XOR swizzle]
    const int lr = lane >> 3;
    const int gc = ((lane & 7) - lr) & 7;

    const bf16* aptr[4]; bf16* alds[4];
    const bf16* bptr[4]; bf16* blds[4];
#pragma unroll
    for (int i = 0; i < 4; ++i) {
        int ci = wave + 4 * i;
        aptr[i] = A + (size_t)(m0 + ci * 8 + lr) * K + gc * 8;
        alds[i] = As + ci * 512;
        bptr[i] = B + (size_t)(n0 + ci * 8 + lr) * K + gc * 8;
        blds[i] = Bs + ci * 512;
    }

    floatx4 acc[4][4] = {};
    const int sw0 = (quad + (l15 & 7)) & 7;   // swizzle base for frag reads
    const bool qk = (n0 < 2 * DM);

    auto kloop = [&](auto swtag) {
        constexpr bool SW = decltype(swtag)::value;
        for (int k0 = 0; k0 < K; k0 += 64) {
            __syncthreads();
#pragma unroll
            for (int i = 0; i < 4; ++i) async_ld16(aptr[i] + k0, alds[i]);
#pragma unroll
            for (int i = 0; i < 4; ++i) async_ld16(bptr[i] + k0, blds[i]);
            __syncthreads();
#pragma unroll
            for (int h = 0; h < 2; ++h) {
                const int so = ((sw0 + 4 * h) & 7) * 8;
                bf16x8 af[4], bfr[4];
#pragma unroll
                for (int i = 0; i < 4; ++i)
                    af[i] = load8(As + (wm + i * 16 + l15) * 64 + so);
#pragma unroll
                for (int j = 0; j < 4; ++j)
                    bfr[j] = load8(Bs + (wn + j * 16 + l15) * 64 + so);
#pragma unroll
                for (int i = 0; i < 4; ++i)
#pragma unroll
                    for (int j = 0; j < 4; ++j)
                        acc[i][j] = SW ? mfma32(bfr[j], af[i], acc[i][j])
                                       : mfma32(af[i], bfr[j], acc[i][j]);
            }
        }
    };
    if (qk) kloop(std::true_type{}); else kloop(std::false_type{});

    const int nb = n0 + wn;   // multiple of 64
    if (qk) {
        // swapped: lane holds 4 consecutive out-cols (head dims) for row s
        bf16* dst = (nb < DM) ? Qh : Kh;
        const int hh = ((nb < DM) ? nb : nb - DM) >> 6;
#pragma unroll
        for (int i = 0; i < 4; ++i) {
            int s = m0 + wm + i * 16 + l15;
            bf16* row = dst + ((size_t)hh * SEQ + s) * 64;
#pragma unroll
            for (int j = 0; j < 4; ++j) {
                int d4 = j * 16 + quad * 4;
                float4 bv = *(const float4*)(bias + nb + d4);
                bf16x4 o = {(bf16)(acc[i][j][0] + bv.x), (bf16)(acc[i][j][1] + bv.y),
                            (bf16)(acc[i][j][2] + bv.z), (bf16)(acc[i][j][3] + bv.w)};
                *(bf16x4*)(row + d4) = o;
            }
        }
    } else {
        // non-swapped: lane holds 4 consecutive s for out-col -> V^T rows
#pragma unroll
        for (int j = 0; j < 4; ++j) {
            int vrow = (nb - 2 * DM) + j * 16 + l15;     // h*64+d, 0..1023
            float bvs = bias[nb + j * 16 + l15];
            bf16* row = Vt + (size_t)vrow * SEQ;
#pragma unroll
            for (int i = 0; i < 4; ++i) {
                int s4 = m0 + wm + i * 16 + quad * 4;
                bf16x4 o = {(bf16)(acc[i][j][0] + bvs), (bf16)(acc[i][j][1] + bvs),
                            (bf16)(acc[i][j][2] + bvs), (bf16)(acc[i][j][3] + bvs)};
                *(bf16x4*)(row + s4) = o;
            }
        }
    }
}

// ---- out-projection GEMM (swapped, row-major fp32 out), BM=64, BK=64.
template <int BM, typename TOUT>
__global__ __launch_bounds__(256) void gemm_sw_kernel(
    const bf16* __restrict__ A, const bf16* __restrict__ B,
    const float* __restrict__ bias, TOUT* __restrict__ C,
    int M, int N, int K)
{
    constexpr int MI = BM / 32;
    __shared__ bf16 As[BM * 64];
    __shared__ bf16 Bs[128 * 64];

    const int tid  = threadIdx.x;
    const int wave = tid >> 6;
    const int lane = tid & 63;
    const int l15  = lane & 15;
    const int quad = lane >> 4;
    const int m0 = blockIdx.x * BM;
    const int n0 = blockIdx.y * 128;
    const int wm = (wave & 1) * (BM / 2);
    const int wn = (wave >> 1) * 64;

    const int lr = lane >> 3;
    const int gc = ((lane & 7) - lr) & 7;

    const bf16* aptr[MI]; bf16* alds[MI];
    const bf16* bptr[4];  bf16* blds[4];
#pragma unroll
    for (int i = 0; i < MI; ++i) {
        int ci = wave + 4 * i;
        aptr[i] = A + (size_t)(m0 + ci * 8 + lr) * K + gc * 8;
        alds[i] = As + ci * 512;
    }
#pragma unroll
    for (int j = 0; j < 4; ++j) {
        int cj = wave + 4 * j;
        bptr[j] = B + (size_t)(n0 + cj * 8 + lr) * K + gc * 8;
        blds[j] = Bs + cj * 512;
    }

    floatx4 acc[MI][4] = {};
    const int sw0 = (quad + (l15 & 7)) & 7;

    for (int k0 = 0; k0 < K; k0 += 64) {
        __syncthreads();
#pragma unroll
        for (int i = 0; i < MI; ++i) async_ld16(aptr[i] + k0, alds[i]);
#pragma unroll
        for (int j = 0; j < 4; ++j) async_ld16(bptr[j] + k0, blds[j]);
        __syncthreads();
#pragma unroll
        for (int h = 0; h < 2; ++h) {
            const int so = ((sw0 + 4 * h) & 7) * 8;
            bf16x8 af[MI], bfr[4];
#pragma unroll
            for (int i = 0; i < MI; ++i)
                af[i] = load8(As + (wm + i * 16 + l15) * 64 + so);
#pragma unroll
            for (int j = 0; j < 4; ++j)
                bfr[j] = load8(Bs + (wn + j * 16 + l15) * 64 + so);
#pragma unroll
            for (int i = 0; i < MI; ++i)
#pragma unroll
                for (int j = 0; j < 4; ++j)
                    acc[i][j] = mfma32(bfr[j], af[i], acc[i][j]);
        }
    }

#pragma unroll
    for (int i = 0; i < MI; ++i) {
        int xm = m0 + wm + i * 16 + l15;
#pragma unroll
        for (int j = 0; j < 4; ++j) {
            int cn = n0 + wn + j * 16 + quad * 4;
            float4 bv = *(const float4*)(bias + cn);
            float v0 = acc[i][j][0] + bv.x;
            float v1 = acc[i][j][1] + bv.y;
            float v2 = acc[i][j][2] + bv.z;
            float v3 = acc[i][j][3] + bv.w;
            if constexpr (sizeof(TOUT) == 2) {
                bf16x4 o = {(bf16)v0, (bf16)v1, (bf16)v2, (bf16)v3};
                *(bf16x4*)((bf16*)C + (size_t)xm * N + cn) = o;
            } else {
                float4 o = {v0, v1, v2, v3};
                *(float4*)((float*)C + (size_t)xm * N + cn) = o;
            }
        }
    }
}

// ---- sliding-window attention, head-major inputs, zero barriers.
// Qh,Kh: [h][s][64]; Vt: [h*64+d][SEQ] (base has 64-elem guard each side).
__global__ __launch_bounds__(256) void swattn_kernel(
    const bf16* __restrict__ Qh, const bf16* __restrict__ Kh,
    const bf16* __restrict__ Vt, bf16* __restrict__ ctx)
{
    __shared__ bf16 Pc[4][16][40];
    __shared__ float lred[4][16];

    const int tid  = threadIdx.x;
    const int wave = tid >> 6;
    const int lane = tid & 63;
    const int l15  = lane & 15;
    const int quad = lane >> 4;
    const int q0   = blockIdx.x * 64;
    const int h    = blockIdx.y;
    const int hoff = h * HD;

    const bf16* qhead = Qh + (size_t)h * SEQ * 64;
    const bf16* khead = Kh + (size_t)h * SEQ * 64;
    const bf16* vhead = Vt + (size_t)hoff * SEQ;

    const int qrow = q0 + wave * 16 + l15;
    bf16x8 aq0 = load8(qhead + (size_t)qrow * 64 + quad * 8);
    bf16x8 aq1 = load8(qhead + (size_t)qrow * 64 + quad * 8 + 32);

    const int ws = q0 - 64 + wave * 16;   // wave window start (global key)
    floatx4 s[9];
#pragma unroll
    for (int st = 0; st < 9; ++st) {
        int kr = ws + st * 16 + l15;
        int kc2 = kr < 0 ? 0 : (kr > SEQ - 1 ? SEQ - 1 : kr);
        const bf16* kp = khead + (size_t)kc2 * 64 + quad * 8;
        bf16x8 b0 = load8(kp), b1 = load8(kp + 32);
        floatx4 acc = {};
        acc = mfma32(aq0, b0, acc);
        acc = mfma32(aq1, b1, acc);
        s[st] = acc;
    }

    // mask + one-shot softmax; row = quad*4+r, key = ws + 16*st + l15
#pragma unroll
    for (int r = 0; r < 4; ++r) {
        int row = quad * 4 + r;
        float mx = -INFINITY;
#pragma unroll
        for (int st = 0; st < 9; ++st) {
            int j = st * 16 + l15;
            int gk = ws + j;
            bool ok = (j >= row) && (j <= 128 + row) && (gk >= 0) && (gk < SEQ);
            float v = ok ? s[st][r] * 0.125f : -1e30f;
            s[st][r] = v;
            mx = fmaxf(mx, v);
        }
        mx = fmaxf(mx, __shfl_xor(mx, 1));
        mx = fmaxf(mx, __shfl_xor(mx, 2));
        mx = fmaxf(mx, __shfl_xor(mx, 4));
        mx = fmaxf(mx, __shfl_xor(mx, 8));
        float sum = 0.f;
#pragma unroll
        for (int st = 0; st < 9; ++st) {
            float p = __expf(s[st][r] - mx);
            s[st][r] = p;
            sum += p;
        }
        sum += __shfl_xor(sum, 1);
        sum += __shfl_xor(sum, 2);
        sum += __shfl_xor(sum, 4);
        sum += __shfl_xor(sum, 8);
        lred[wave][row] = sum;   // wave-private slot, wave-ordered LDS
    }

    // PV, operand-swapped: a = V^T frag straight from global, b = P frag.
    floatx4 ot[4] = {};
#pragma unroll
    for (int kc = 0; kc < 5; ++kc) {
#pragma unroll
        for (int r = 0; r < 4; ++r) {
            int row = quad * 4 + r;
            Pc[wave][row][l15] = (bf16)s[2 * kc][r];
            Pc[wave][row][16 + l15] = (kc < 4) ? (bf16)s[2 * kc + 1][r] : (bf16)0.f;
        }
        bf16x8 pb = load8(&Pc[wave][l15][quad * 8]);
#pragma unroll
        for (int dt = 0; dt < 4; ++dt) {
            const bf16* vp = vhead + (ptrdiff_t)(dt * 16 + l15) * SEQ
                                   + (ptrdiff_t)(ws + kc * 32 + quad * 8);
            ot[dt] = mfma32(load8(vp), pb, ot[dt]);
        }
    }

    float linv = 1.0f / lred[wave][l15];
#pragma unroll
    for (int dt = 0; dt < 4; ++dt) {
        bf16x4 o4;
#pragma unroll
        for (int r = 0; r < 4; ++r) o4[r] = (bf16)(ot[dt][r] * linv);
        *(bf16x4*)(ctx + (size_t)qrow * DM + hoff + dt * 16 + quad * 4) = o4;
    }
}

extern "C" void kernel_launch(void* const* d_in, const int* in_sizes, int n_in,
                              void* d_out, int out_size, void* d_ws, size_t ws_size,
                              hipStream_t stream) {
    const float* x  = (const float*)d_in[0];
    const float* Wq = (const float*)d_in[1];
    const float* bq = (const float*)d_in[2];
    const float* Wk = (const float*)d_in[3];
    const float* bk = (const float*)d_in[4];
    const float* Wv = (const float*)d_in[5];
    const float* bv = (const float*)d_in[6];
    const float* Wo = (const float*)d_in[7];
    const float* bo = (const float*)d_in[8];
    float* out = (float*)d_out;

    const size_t XN = (size_t)SEQ * DM;
    const size_t WN = (size_t)DM * DM;

    bf16* xb    = (bf16*)d_ws;            // XN ; reused as ctx after QKV GEMM
    bf16* Wcat  = xb + XN;                // 3*WN
    bf16* Wob   = Wcat + 3 * WN;          // WN
    bf16* Qh    = Wob + WN;               // XN
    bf16* Kh    = Qh + XN;                // XN
    bf16* VtRaw = Kh + XN;                // XN + 2*GUARD + 128
    bf16* Vtb   = VtRaw + GUARD;
    float* bcat = (float*)(VtRaw + XN + 2 * GUARD + 128);  // 3072 fp32
    bf16* ctx   = xb;                     // alias: xb dead after QKV GEMM

    prep_kernel<<<4097, 256, 0, stream>>>(x, Wq, Wk, Wv, Wo, bq, bk, bv,
                                          xb, Wcat, Wob, bcat);

    gemm_qkv_kernel<<<dim3(SEQ / 128, 24), 256, 0, stream>>>(
        xb, Wcat, bcat, Qh, Kh, Vtb);

    swattn_kernel<<<dim3(SEQ / 64, NH), 256, 0, stream>>>(Qh, Kh, Vtb, ctx);

    gemm_sw_kernel<64, float><<<dim3(SEQ / 64, DM / 128), 256, 0, stream>>>(
        ctx, Wob, bo, out, SEQ, DM, DM);
}

// Round 7
// 160.994 us; speedup vs baseline: 1.9421x; 1.0621x over previous
//
#include <hip/hip_runtime.h>
#include <type_traits>

typedef __bf16 bf16;
typedef __bf16 bf16x8 __attribute__((ext_vector_type(8)));
typedef __bf16 bf16x4 __attribute__((ext_vector_type(4)));
typedef float floatx4 __attribute__((ext_vector_type(4)));

#define SEQ 4096
#define DM 1024
#define NH 16
#define HD 64
#define GUARD 64

__device__ __forceinline__ floatx4 mfma32(bf16x8 a, bf16x8 b, floatx4 c) {
    return __builtin_amdgcn_mfma_f32_16x16x32_bf16(a, b, c, 0, 0, 0);
}

__device__ __forceinline__ bf16x8 load8(const bf16* p) {
    return *(const bf16x8*)p;
}

__device__ __forceinline__ void async_ld16(const bf16* g, bf16* l) {
    __builtin_amdgcn_global_load_lds(
        (const __attribute__((address_space(1))) unsigned int*)g,
        (__attribute__((address_space(3))) unsigned int*)l,
        16, 0, 0);
}

// fused prep: cast x, Wq,Wk,Wv,Wo to bf16; concat biases to fp32 bcat.
__global__ __launch_bounds__(256) void prep_kernel(
    const float* __restrict__ x,  const float* __restrict__ Wq,
    const float* __restrict__ Wk, const float* __restrict__ Wv,
    const float* __restrict__ Wo, const float* __restrict__ bq,
    const float* __restrict__ bk, const float* __restrict__ bv,
    bf16* __restrict__ xb, bf16* __restrict__ Wcat,
    bf16* __restrict__ Wob, float* __restrict__ bcat)
{
    const int WN8 = 131072;           // (1024*1024)/8
    const int XN8 = 524288;           // (4096*1024)/8
    int b = blockIdx.x;
    if (b == 4096) {
        for (int k = threadIdx.x; k < 3 * DM; k += 256)
            bcat[k] = k < DM ? bq[k] : (k < 2 * DM ? bk[k - DM] : bv[k - 2 * DM]);
        return;
    }
    int c = b * 256 + threadIdx.x;
    const float* src; bf16* dst;
    if (c < XN8)              { src = x;  dst = xb; }
    else if (c < XN8 + WN8)   { src = Wq; dst = Wcat;                 c -= XN8; }
    else if (c < XN8 + 2*WN8) { src = Wk; dst = Wcat + (size_t)DM*DM;     c -= XN8 + WN8; }
    else if (c < XN8 + 3*WN8) { src = Wv; dst = Wcat + (size_t)2*DM*DM;   c -= XN8 + 2*WN8; }
    else                      { src = Wo; dst = Wob;                  c -= XN8 + 3*WN8; }
    float4 a = ((const float4*)src)[2 * c], d2 = ((const float4*)src)[2 * c + 1];
    bf16x8 o;
    o[0] = (bf16)a.x;  o[1] = (bf16)a.y;  o[2] = (bf16)a.z;  o[3] = (bf16)a.w;
    o[4] = (bf16)d2.x; o[5] = (bf16)d2.y; o[6] = (bf16)d2.z; o[7] = (bf16)d2.w;
    *(bf16x8*)(dst + 8 * (size_t)c) = o;
}

// ---- QKV projection GEMM: [4096,1024] @ [3072,1024]^T, head-major outputs.
// BM=128, BN=128, BK=64, XOR-swizzled LDS (0 bank conflicts, verified r6).
// launch_bounds(256,3): cap regs at 170 so 3 blocks/CU are resident.
__global__ __launch_bounds__(256, 3) void gemm_qkv_kernel(
    const bf16* __restrict__ A,      // xb [4096][1024]
    const bf16* __restrict__ B,      // Wcat [3072][1024]
    const float* __restrict__ bias,  // bcat [3072]
    bf16* __restrict__ Qh, bf16* __restrict__ Kh, bf16* __restrict__ Vt)
{
    constexpr int K = DM;
    __shared__ bf16 As[128 * 64];
    __shared__ bf16 Bs[128 * 64];

    const int tid  = threadIdx.x;
    const int wave = tid >> 6;
    const int lane = tid & 63;
    const int l15  = lane & 15;
    const int quad = lane >> 4;
    const int m0 = blockIdx.x * 128;
    const int n0 = blockIdx.y * 128;
    const int wm = (wave & 1) * 64;
    const int wn = (wave >> 1) * 64;

    // staging: chunk = 8 rows x 64 cols (1024B). lane -> (row lane>>3,
    // LDS slot lane&7); global col chunk gc = (slot - row)&7  [XOR swizzle]
    const int lr = lane >> 3;
    const int gc = ((lane & 7) - lr) & 7;

    const bf16* aptr[4]; bf16* alds[4];
    const bf16* bptr[4]; bf16* blds[4];
#pragma unroll
    for (int i = 0; i < 4; ++i) {
        int ci = wave + 4 * i;
        aptr[i] = A + (size_t)(m0 + ci * 8 + lr) * K + gc * 8;
        alds[i] = As + ci * 512;
        bptr[i] = B + (size_t)(n0 + ci * 8 + lr) * K + gc * 8;
        blds[i] = Bs + ci * 512;
    }

    floatx4 acc[4][4] = {};
    const int sw0 = (quad + (l15 & 7)) & 7;   // swizzle base for frag reads
    const bool qk = (n0 < 2 * DM);

    auto kloop = [&](auto swtag) {
        constexpr bool SW = decltype(swtag)::value;
        for (int k0 = 0; k0 < K; k0 += 64) {
            __syncthreads();
#pragma unroll
            for (int i = 0; i < 4; ++i) async_ld16(aptr[i] + k0, alds[i]);
#pragma unroll
            for (int i = 0; i < 4; ++i) async_ld16(bptr[i] + k0, blds[i]);
            __syncthreads();
#pragma unroll
            for (int h = 0; h < 2; ++h) {
                const int so = ((sw0 + 4 * h) & 7) * 8;
                bf16x8 af[4], bfr[4];
#pragma unroll
                for (int i = 0; i < 4; ++i)
                    af[i] = load8(As + (wm + i * 16 + l15) * 64 + so);
#pragma unroll
                for (int j = 0; j < 4; ++j)
                    bfr[j] = load8(Bs + (wn + j * 16 + l15) * 64 + so);
#pragma unroll
                for (int i = 0; i < 4; ++i)
#pragma unroll
                    for (int j = 0; j < 4; ++j)
                        acc[i][j] = SW ? mfma32(bfr[j], af[i], acc[i][j])
                                       : mfma32(af[i], bfr[j], acc[i][j]);
            }
        }
    };
    if (qk) kloop(std::true_type{}); else kloop(std::false_type{});

    const int nb = n0 + wn;   // multiple of 64
    if (qk) {
        // swapped: lane holds 4 consecutive out-cols (head dims) for row s
        bf16* dst = (nb < DM) ? Qh : Kh;
        const int hh = ((nb < DM) ? nb : nb - DM) >> 6;
#pragma unroll
        for (int i = 0; i < 4; ++i) {
            int s = m0 + wm + i * 16 + l15;
            bf16* row = dst + ((size_t)hh * SEQ + s) * 64;
#pragma unroll
            for (int j = 0; j < 4; ++j) {
                int d4 = j * 16 + quad * 4;
                float4 bv = *(const float4*)(bias + nb + d4);
                bf16x4 o = {(bf16)(acc[i][j][0] + bv.x), (bf16)(acc[i][j][1] + bv.y),
                            (bf16)(acc[i][j][2] + bv.z), (bf16)(acc[i][j][3] + bv.w)};
                *(bf16x4*)(row + d4) = o;
            }
        }
    } else {
        // non-swapped: lane holds 4 consecutive s for out-col -> V^T rows
#pragma unroll
        for (int j = 0; j < 4; ++j) {
            int vrow = (nb - 2 * DM) + j * 16 + l15;     // h*64+d, 0..1023
            float bvs = bias[nb + j * 16 + l15];
            bf16* row = Vt + (size_t)vrow * SEQ;
#pragma unroll
            for (int i = 0; i < 4; ++i) {
                int s4 = m0 + wm + i * 16 + quad * 4;
                bf16x4 o = {(bf16)(acc[i][j][0] + bvs), (bf16)(acc[i][j][1] + bvs),
                            (bf16)(acc[i][j][2] + bvs), (bf16)(acc[i][j][3] + bvs)};
                *(bf16x4*)(row + s4) = o;
            }
        }
    }
}

// ---- out-projection GEMM (swapped, row-major fp32 out), BM=64, BK=64.
template <int BM, typename TOUT>
__global__ __launch_bounds__(256, 4) void gemm_sw_kernel(
    const bf16* __restrict__ A, const bf16* __restrict__ B,
    const float* __restrict__ bias, TOUT* __restrict__ C,
    int M, int N, int K)
{
    constexpr int MI = BM / 32;
    __shared__ bf16 As[BM * 64];
    __shared__ bf16 Bs[128 * 64];

    const int tid  = threadIdx.x;
    const int wave = tid >> 6;
    const int lane = tid & 63;
    const int l15  = lane & 15;
    const int quad = lane >> 4;
    const int m0 = blockIdx.x * BM;
    const int n0 = blockIdx.y * 128;
    const int wm = (wave & 1) * (BM / 2);
    const int wn = (wave >> 1) * 64;

    const int lr = lane >> 3;
    const int gc = ((lane & 7) - lr) & 7;

    const bf16* aptr[MI]; bf16* alds[MI];
    const bf16* bptr[4];  bf16* blds[4];
#pragma unroll
    for (int i = 0; i < MI; ++i) {
        int ci = wave + 4 * i;
        aptr[i] = A + (size_t)(m0 + ci * 8 + lr) * K + gc * 8;
        alds[i] = As + ci * 512;
    }
#pragma unroll
    for (int j = 0; j < 4; ++j) {
        int cj = wave + 4 * j;
        bptr[j] = B + (size_t)(n0 + cj * 8 + lr) * K + gc * 8;
        blds[j] = Bs + cj * 512;
    }

    floatx4 acc[MI][4] = {};
    const int sw0 = (quad + (l15 & 7)) & 7;

    for (int k0 = 0; k0 < K; k0 += 64) {
        __syncthreads();
#pragma unroll
        for (int i = 0; i < MI; ++i) async_ld16(aptr[i] + k0, alds[i]);
#pragma unroll
        for (int j = 0; j < 4; ++j) async_ld16(bptr[j] + k0, blds[j]);
        __syncthreads();
#pragma unroll
        for (int h = 0; h < 2; ++h) {
            const int so = ((sw0 + 4 * h) & 7) * 8;
            bf16x8 af[MI], bfr[4];
#pragma unroll
            for (int i = 0; i < MI; ++i)
                af[i] = load8(As + (wm + i * 16 + l15) * 64 + so);
#pragma unroll
            for (int j = 0; j < 4; ++j)
                bfr[j] = load8(Bs + (wn + j * 16 + l15) * 64 + so);
#pragma unroll
            for (int i = 0; i < MI; ++i)
#pragma unroll
                for (int j = 0; j < 4; ++j)
                    acc[i][j] = mfma32(bfr[j], af[i], acc[i][j]);
        }
    }

#pragma unroll
    for (int i = 0; i < MI; ++i) {
        int xm = m0 + wm + i * 16 + l15;
#pragma unroll
        for (int j = 0; j < 4; ++j) {
            int cn = n0 + wn + j * 16 + quad * 4;
            float4 bv = *(const float4*)(bias + cn);
            float v0 = acc[i][j][0] + bv.x;
            float v1 = acc[i][j][1] + bv.y;
            float v2 = acc[i][j][2] + bv.z;
            float v3 = acc[i][j][3] + bv.w;
            if constexpr (sizeof(TOUT) == 2) {
                bf16x4 o = {(bf16)v0, (bf16)v1, (bf16)v2, (bf16)v3};
                *(bf16x4*)((bf16*)C + (size_t)xm * N + cn) = o;
            } else {
                float4 o = {v0, v1, v2, v3};
                *(float4*)((float*)C + (size_t)xm * N + cn) = o;
            }
        }
    }
}

// ---- sliding-window attention, head-major inputs, zero barriers.
// Qh,Kh: [h][s][64]; Vt: [h*64+d][SEQ] (base has 64-elem guard each side).
__global__ __launch_bounds__(256) void swattn_kernel(
    const bf16* __restrict__ Qh, const bf16* __restrict__ Kh,
    const bf16* __restrict__ Vt, bf16* __restrict__ ctx)
{
    __shared__ bf16 Pc[4][16][40];
    __shared__ float lred[4][16];

    const int tid  = threadIdx.x;
    const int wave = tid >> 6;
    const int lane = tid & 63;
    const int l15  = lane & 15;
    const int quad = lane >> 4;
    const int q0   = blockIdx.x * 64;
    const int h    = blockIdx.y;
    const int hoff = h * HD;

    const bf16* qhead = Qh + (size_t)h * SEQ * 64;
    const bf16* khead = Kh + (size_t)h * SEQ * 64;
    const bf16* vhead = Vt + (size_t)hoff * SEQ;

    const int qrow = q0 + wave * 16 + l15;
    bf16x8 aq0 = load8(qhead + (size_t)qrow * 64 + quad * 8);
    bf16x8 aq1 = load8(qhead + (size_t)qrow * 64 + quad * 8 + 32);

    const int ws = q0 - 64 + wave * 16;   // wave window start (global key)
    floatx4 s[9];
#pragma unroll
    for (int st = 0; st < 9; ++st) {
        int kr = ws + st * 16 + l15;
        int kc2 = kr < 0 ? 0 : (kr > SEQ - 1 ? SEQ - 1 : kr);
        const bf16* kp = khead + (size_t)kc2 * 64 + quad * 8;
        bf16x8 b0 = load8(kp), b1 = load8(kp + 32);
        floatx4 acc = {};
        acc = mfma32(aq0, b0, acc);
        acc = mfma32(aq1, b1, acc);
        s[st] = acc;
    }

    // mask + one-shot softmax; row = quad*4+r, key = ws + 16*st + l15
#pragma unroll
    for (int r = 0; r < 4; ++r) {
        int row = quad * 4 + r;
        float mx = -INFINITY;
#pragma unroll
        for (int st = 0; st < 9; ++st) {
            int j = st * 16 + l15;
            int gk = ws + j;
            bool ok = (j >= row) && (j <= 128 + row) && (gk >= 0) && (gk < SEQ);
            float v = ok ? s[st][r] * 0.125f : -1e30f;
            s[st][r] = v;
            mx = fmaxf(mx, v);
        }
        mx = fmaxf(mx, __shfl_xor(mx, 1));
        mx = fmaxf(mx, __shfl_xor(mx, 2));
        mx = fmaxf(mx, __shfl_xor(mx, 4));
        mx = fmaxf(mx, __shfl_xor(mx, 8));
        float sum = 0.f;
#pragma unroll
        for (int st = 0; st < 9; ++st) {
            float p = __expf(s[st][r] - mx);
            s[st][r] = p;
            sum += p;
        }
        sum += __shfl_xor(sum, 1);
        sum += __shfl_xor(sum, 2);
        sum += __shfl_xor(sum, 4);
        sum += __shfl_xor(sum, 8);
        lred[wave][row] = sum;   // wave-private slot, wave-ordered LDS
    }

    // PV, operand-swapped: a = V^T frag straight from global, b = P frag.
    floatx4 ot[4] = {};
#pragma unroll
    for (int kc = 0; kc < 5; ++kc) {
#pragma unroll
        for (int r = 0; r < 4; ++r) {
            int row = quad * 4 + r;
            Pc[wave][row][l15] = (bf16)s[2 * kc][r];
            Pc[wave][row][16 + l15] = (kc < 4) ? (bf16)s[2 * kc + 1][r] : (bf16)0.f;
        }
        bf16x8 pb = load8(&Pc[wave][l15][quad * 8]);
#pragma unroll
        for (int dt = 0; dt < 4; ++dt) {
            const bf16* vp = vhead + (ptrdiff_t)(dt * 16 + l15) * SEQ
                                   + (ptrdiff_t)(ws + kc * 32 + quad * 8);
            ot[dt] = mfma32(load8(vp), pb, ot[dt]);
        }
    }

    float linv = 1.0f / lred[wave][l15];
#pragma unroll
    for (int dt = 0; dt < 4; ++dt) {
        bf16x4 o4;
#pragma unroll
        for (int r = 0; r < 4; ++r) o4[r] = (bf16)(ot[dt][r] * linv);
        *(bf16x4*)(ctx + (size_t)qrow * DM + hoff + dt * 16 + quad * 4) = o4;
    }
}

extern "C" void kernel_launch(void* const* d_in, const int* in_sizes, int n_in,
                              void* d_out, int out_size, void* d_ws, size_t ws_size,
                              hipStream_t stream) {
    const float* x  = (const float*)d_in[0];
    const float* Wq = (const float*)d_in[1];
    const float* bq = (const float*)d_in[2];
    const float* Wk = (const float*)d_in[3];
    const float* bk = (const float*)d_in[4];
    const float* Wv = (const float*)d_in[5];
    const float* bv = (const float*)d_in[6];
    const float* Wo = (const float*)d_in[7];
    const float* bo = (const float*)d_in[8];
    float* out = (float*)d_out;

    const size_t XN = (size_t)SEQ * DM;
    const size_t WN = (size_t)DM * DM;

    bf16* xb    = (bf16*)d_ws;            // XN ; reused as ctx after QKV GEMM
    bf16* Wcat  = xb + XN;                // 3*WN
    bf16* Wob   = Wcat + 3 * WN;          // WN
    bf16* Qh    = Wob + WN;               // XN
    bf16* Kh    = Qh + XN;                // XN
    bf16* VtRaw = Kh + XN;                // XN + 2*GUARD + 128
    bf16* Vtb   = VtRaw + GUARD;
    float* bcat = (float*)(VtRaw + XN + 2 * GUARD + 128);  // 3072 fp32
    bf16* ctx   = xb;                     // alias: xb dead after QKV GEMM

    prep_kernel<<<4097, 256, 0, stream>>>(x, Wq, Wk, Wv, Wo, bq, bk, bv,
                                          xb, Wcat, Wob, bcat);

    gemm_qkv_kernel<<<dim3(SEQ / 128, 24), 256, 0, stream>>>(
        xb, Wcat, bcat, Qh, Kh, Vtb);

    swattn_kernel<<<dim3(SEQ / 64, NH), 256, 0, stream>>>(Qh, Kh, Vtb, ctx);

    gemm_sw_kernel<64, float><<<dim3(SEQ / 64, DM / 128), 256, 0, stream>>>(
        ctx, Wob, bo, out, SEQ, DM, DM);
}